// Round 8
// baseline (102.918 us; speedup 1.0000x reference)
//
#include <hip/hip_runtime.h>
#include <hip/hip_fp16.h>
#include <math.h>

#define BB 4
#define CC 256
#define HH 100
#define WW 100
#define HWP (HH * WW)
#define NPIX (BB * HWP)

#define XT_BYTES ((size_t)NPIX * CC * 2)          // 20,480,000
#define GEOM_BYTES ((size_t)NPIX * 9 * 32)        // 11,520,000

#define NT_BLOCKS (BB * HH)                       // 400 transpose blocks
#define NG_BLOCKS ((NPIX + 255) / 256)            // 157 geom blocks

#define TILE 8                                    // 8x8 pixel tile per block
#define HALO 16                                   // 16x16 staged positions
#define TPD 13                                    // ceil(100/8) tiles per dim
#define TPI (TPD * TPD)                           // 169 tiles per image
#define HALO_BYTES (HALO * HALO * CC * 2)         // 131072 = 128 KiB

// ROCm 7.2 hip_fp16.h lacks __hmax2 — emit v_pk_max_f16 directly.
static __device__ inline uint pk_max_f16(uint a, uint b) {
    uint r;
    asm("v_pk_max_f16 %0, %1, %2" : "=v"(r) : "v"(a), "v"(b));
    return r;
}

// ---------------------------------------------------------------------------
// Prep kernel: blocks [0,400) transpose+convert x -> xT fp16 channel-last;
// blocks [400, 400+157) compute per-(pixel,tap) geometry records:
//   rec0 = { packed clamped coords (yc0|yc1<<8|xc0<<16|xc1<<24),
//            o00 bytes, o10 bytes, (xc1-xc0)*512 }   (fallback info)
//   rec1 = { w00, w01, w10, w11 } as broadcast half2
// ---------------------------------------------------------------------------
__global__ __launch_bounds__(256) void prep_kernel(
    const float* __restrict__ x, ushort* __restrict__ xT,
    const float* __restrict__ off, int4* __restrict__ geom) {
    __shared__ uint tileT[WW][CC / 2 + 1];   // 51.6 KB

    if (blockIdx.x < NT_BLOCKS) {
        int bh = blockIdx.x;                 // 0..B*H-1
        int b = bh / HH;
        int h = bh - b * HH;
        const float* src = x + (size_t)b * CC * HWP + (size_t)h * WW;

        for (int idx = threadIdx.x; idx < (CC / 2) * 25; idx += 256) {
            int c2 = idx / 25;
            int w4 = idx - c2 * 25;
            const float* p0 = src + (size_t)(2 * c2) * HWP + w4 * 4;
            float4 va = *reinterpret_cast<const float4*>(p0);        // ch 2*c2
            float4 vb = *reinterpret_cast<const float4*>(p0 + HWP);  // ch 2*c2+1
            __half2 h0 = __floats2half2_rn(va.x, vb.x);
            __half2 h1 = __floats2half2_rn(va.y, vb.y);
            __half2 h2 = __floats2half2_rn(va.z, vb.z);
            __half2 h3 = __floats2half2_rn(va.w, vb.w);
            tileT[w4 * 4 + 0][c2] = *reinterpret_cast<uint*>(&h0);
            tileT[w4 * 4 + 1][c2] = *reinterpret_cast<uint*>(&h1);
            tileT[w4 * 4 + 2][c2] = *reinterpret_cast<uint*>(&h2);
            tileT[w4 * 4 + 3][c2] = *reinterpret_cast<uint*>(&h3);
        }
        __syncthreads();

        uint2* dst = reinterpret_cast<uint2*>(xT + (size_t)bh * WW * CC);
        for (int idx = threadIdx.x; idx < WW * (CC / 4); idx += 256) {
            int w = idx >> 6;           // CC/4 = 64
            int c4 = idx & 63;
            dst[idx] = make_uint2(tileT[w][2 * c4], tileT[w][2 * c4 + 1]);
        }
        return;
    }

    // ---- geometry part ----
    int p = (blockIdx.x - NT_BLOCKS) * 256 + threadIdx.x;
    if (p >= NPIX) return;
    int b = p / HWP;
    int hw = p - b * HWP;
    int h = hw / WW;
    int w = hw - h * WW;
    const float* offp = off + (size_t)b * 18 * HWP + hw;
    int bH = b * HH;
#pragma unroll
    for (int k = 0; k < 9; ++k) {
        int kh = k / 3 - 1;
        int kw = k - (k / 3) * 3 - 1;
        float dy = offp[(size_t)(2 * k) * HWP];
        float dx = offp[(size_t)(2 * k + 1) * HWP];
        float py = (float)(h + kh) + dy;
        float px = (float)(w + kw) + dx;
        float y0f = floorf(py), x0f = floorf(px);
        float wy = py - y0f, wx = px - x0f;
        int y0 = (int)y0f, x0 = (int)x0f;
        int y1 = y0 + 1, x1 = x0 + 1;
        bool vy0 = (y0 >= 0) && (y0 < HH);
        bool vy1 = (y1 >= 0) && (y1 < HH);
        bool vx0 = (x0 >= 0) && (x0 < WW);
        bool vx1 = (x1 >= 0) && (x1 < WW);
        int yc0 = min(max(y0, 0), HH - 1);
        int yc1 = min(max(y1, 0), HH - 1);
        int xc0 = min(max(x0, 0), WW - 1);
        int xc1 = min(max(x1, 0), WW - 1);
        float w00 = (1.f - wy) * (1.f - wx) * (float)(vy0 && vx0);
        float w01 = (1.f - wy) * wx * (float)(vy0 && vx1);
        float w10 = wy * (1.f - wx) * (float)(vy1 && vx0);
        float w11 = wy * wx * (float)(vy1 && vx1);
        int o00 = ((bH + yc0) * WW + xc0) * (CC * 2);
        int o10 = ((bH + yc1) * WW + xc0) * (CC * 2);
        int dx5 = (xc1 - xc0) * (CC * 2);
        int packed = yc0 | (yc1 << 8) | (xc0 << 16) | (xc1 << 24);
        __half2 h00 = __floats2half2_rn(w00, w00);
        __half2 h01 = __floats2half2_rn(w01, w01);
        __half2 h10 = __floats2half2_rn(w10, w10);
        __half2 h11 = __floats2half2_rn(w11, w11);
        int4* rec = geom + ((size_t)p * 9 + k) * 2;
        rec[0] = make_int4(packed, o00, o10, dx5);
        rec[1] = make_int4(*reinterpret_cast<int*>(&h00), *reinterpret_cast<int*>(&h01),
                           *reinterpret_cast<int*>(&h10), *reinterpret_cast<int*>(&h11));
    }
}

// ---------------------------------------------------------------------------
// Tiled pass 2: one 1024-thread block per 8x8 pixel tile. Stage the 16x16
// halo (128 KiB: 256 rows of 512 B = all channels at one (y,x)) in LDS, then
// each wave processes 4 pixels: 9 taps x 4 corner ds_read_b64 (conflict-free)
// + packed fp16 bilinear/max. Out-of-halo taps (p~0.3%) take a wave-uniform
// scalar branch to global. R7 lesson: 47.5us was an L2-path byte ceiling
// (737 MB @ 15.5 TB/s); LDS amplifies the 36x reuse instead.
// ---------------------------------------------------------------------------
__global__ __launch_bounds__(1024) void deform_tiled_kernel(
    const char* __restrict__ xTb, const int4* __restrict__ geom,
    const float* __restrict__ w0, const float* __restrict__ b0,
    float* __restrict__ out) {
    extern __shared__ char halo[];           // HALO_BYTES

    int blk = blockIdx.x;
    int b = blk / TPI;
    int t = blk - b * TPI;
    int tyi = t / TPD;
    int ty = tyi * TILE;
    int tx = (t - tyi * TPD) * TILE;
    int sy = min(max(ty - 4, 0), HH - HALO);
    int sx = min(max(tx - 4, 0), WW - HALO);

    // ---- stage halo: 16 y-strips, each 16 x-positions = 8 KB contiguous ----
    {
        const char* base = xTb + (((size_t)(b * HH + sy) * WW + sx) << 9);
        int tid = threadIdx.x;
#pragma unroll
        for (int it = 0; it < 8; ++it) {
            int i = tid + it * 1024;         // 0..8191 (uint4 elements)
            int strip = i >> 9;              // 512 x 16B per strip
            int within = i & 511;
            uint4 v = *reinterpret_cast<const uint4*>(
                base + (size_t)strip * (WW * 512) + ((size_t)within << 4));
            *reinterpret_cast<uint4*>(halo + ((size_t)i << 4)) = v;
        }
    }
    __syncthreads();

    int lane = threadIdx.x & 63;
    int wv = threadIdx.x >> 6;               // 0..15
    int laneOff = lane * 8;
    float4 wq = reinterpret_cast<const float4*>(w0)[lane];  // ch 4l..4l+3
    float bias = b0[0];

    for (int j = 0; j < 4; ++j) {
        int idx = wv * 4 + j;
        int r = idx >> 3, c = idx & 7;
        int h = ty + r, wc = tx + c;
        if (h >= HH || wc >= WW) continue;   // wave-uniform
        int p = b * HWP + h * WW + wc;
        const int4* g = geom + (size_t)p * 18;

        uint m0 = 0xFC00FC00u, m1 = 0xFC00FC00u;
#pragma unroll
        for (int k = 0; k < 9; ++k) {
            int4 r0 = g[2 * k];
            int4 wbr = g[2 * k + 1];
            int packed = __builtin_amdgcn_readfirstlane(r0.x);
            int yc0 = packed & 0xff, yc1 = (packed >> 8) & 0xff;
            int xc0 = (packed >> 16) & 0xff, xc1 = (packed >> 24) & 0xff;
            uint2 u00, u01, u10, u11;
            if (yc0 >= sy && yc1 <= sy + (HALO - 1) &&
                xc0 >= sx && xc1 <= sx + (HALO - 1)) {
                int ry0 = (yc0 - sy) << 4, ry1 = (yc1 - sy) << 4;
                int cx0 = xc0 - sx, cx1 = xc1 - sx;
                u00 = *reinterpret_cast<const uint2*>(halo + (((ry0 + cx0) << 9) + laneOff));
                u01 = *reinterpret_cast<const uint2*>(halo + (((ry0 + cx1) << 9) + laneOff));
                u10 = *reinterpret_cast<const uint2*>(halo + (((ry1 + cx0) << 9) + laneOff));
                u11 = *reinterpret_cast<const uint2*>(halo + (((ry1 + cx1) << 9) + laneOff));
            } else {
                int o00 = __builtin_amdgcn_readfirstlane(r0.y);
                int o10 = __builtin_amdgcn_readfirstlane(r0.z);
                int dx5 = __builtin_amdgcn_readfirstlane(r0.w);
                u00 = *reinterpret_cast<const uint2*>(xTb + o00 + laneOff);
                u01 = *reinterpret_cast<const uint2*>(xTb + o00 + dx5 + laneOff);
                u10 = *reinterpret_cast<const uint2*>(xTb + o10 + laneOff);
                u11 = *reinterpret_cast<const uint2*>(xTb + o10 + dx5 + laneOff);
            }

            __half2 w00 = *reinterpret_cast<__half2*>(&wbr.x);
            __half2 w01 = *reinterpret_cast<__half2*>(&wbr.y);
            __half2 w10 = *reinterpret_cast<__half2*>(&wbr.z);
            __half2 w11 = *reinterpret_cast<__half2*>(&wbr.w);

            __half2 a; uint au;
            au = u00.x; a = *reinterpret_cast<__half2*>(&au);
            __half2 acc0 = __hmul2(a, w00);
            au = u00.y; a = *reinterpret_cast<__half2*>(&au);
            __half2 acc1 = __hmul2(a, w00);
            au = u01.x; a = *reinterpret_cast<__half2*>(&au);
            acc0 = __hfma2(a, w01, acc0);
            au = u01.y; a = *reinterpret_cast<__half2*>(&au);
            acc1 = __hfma2(a, w01, acc1);
            au = u10.x; a = *reinterpret_cast<__half2*>(&au);
            acc0 = __hfma2(a, w10, acc0);
            au = u10.y; a = *reinterpret_cast<__half2*>(&au);
            acc1 = __hfma2(a, w10, acc1);
            au = u11.x; a = *reinterpret_cast<__half2*>(&au);
            acc0 = __hfma2(a, w11, acc0);
            au = u11.y; a = *reinterpret_cast<__half2*>(&au);
            acc1 = __hfma2(a, w11, acc1);

            m0 = pk_max_f16(m0, *reinterpret_cast<uint*>(&acc0));
            m1 = pk_max_f16(m1, *reinterpret_cast<uint*>(&acc1));
        }

        float2 f0 = __half22float2(*reinterpret_cast<__half2*>(&m0)); // ch 4l,4l+1
        float2 f1 = __half22float2(*reinterpret_cast<__half2*>(&m1)); // ch 4l+2,4l+3
        float part = f0.x * wq.x + f0.y * wq.y + f1.x * wq.z + f1.y * wq.w;
#pragma unroll
        for (int d = 32; d > 0; d >>= 1) part += __shfl_down(part, d, 64);
        if (lane == 0) {
            float z = part + bias;
            out[p] = 1.f / (1.f + expf(-z));
        }
    }
}

// ---------------------------------------------------------------------------
// Fallback: one block (128 threads) per pixel, f32 path, no workspace needed.
// ---------------------------------------------------------------------------
__global__ __launch_bounds__(128) void deform_fallback_kernel(
    const float* __restrict__ x, const float* __restrict__ off,
    const float* __restrict__ w0, const float* __restrict__ b0,
    float* __restrict__ out) {
    int p = blockIdx.x;
    int b = p / HWP;
    int hw = p - b * HWP;
    int h = hw / WW;
    int w = hw - h * WW;
    int tid = threadIdx.x;

    const float* offp = off + (size_t)b * 18 * HWP + hw;
    const float* xb = x + (size_t)b * CC * HWP + (size_t)(2 * tid) * HWP;

    float m0 = -INFINITY, m1 = -INFINITY;

#pragma unroll
    for (int k = 0; k < 9; ++k) {
        int kh = k / 3 - 1;
        int kw = k - (k / 3) * 3 - 1;
        float dy = offp[(size_t)(2 * k) * HWP];
        float dx = offp[(size_t)(2 * k + 1) * HWP];
        float py = (float)(h + kh) + dy;
        float px = (float)(w + kw) + dx;
        float y0f = floorf(py), x0f = floorf(px);
        float wy = py - y0f, wx = px - x0f;
        int y0 = (int)y0f, x0 = (int)x0f;
        int y1 = y0 + 1, x1 = x0 + 1;
        bool vy0 = (y0 >= 0) && (y0 < HH);
        bool vy1 = (y1 >= 0) && (y1 < HH);
        bool vx0 = (x0 >= 0) && (x0 < WW);
        bool vx1 = (x1 >= 0) && (x1 < WW);
        int yc0 = min(max(y0, 0), HH - 1);
        int yc1 = min(max(y1, 0), HH - 1);
        int xc0 = min(max(x0, 0), WW - 1);
        int xc1 = min(max(x1, 0), WW - 1);
        float w00 = (1.f - wy) * (1.f - wx) * (float)(vy0 && vx0);
        float w01 = (1.f - wy) * wx * (float)(vy0 && vx1);
        float w10 = wy * (1.f - wx) * (float)(vy1 && vx0);
        float w11 = wy * wx * (float)(vy1 && vx1);

        int o00 = yc0 * WW + xc0, o01 = yc0 * WW + xc1;
        int o10 = yc1 * WW + xc0, o11 = yc1 * WW + xc1;
        float s0 = xb[o00] * w00 + xb[o01] * w01 + xb[o10] * w10 + xb[o11] * w11;
        float s1 = xb[o00 + HWP] * w00 + xb[o01 + HWP] * w01 +
                   xb[o10 + HWP] * w10 + xb[o11 + HWP] * w11;
        m0 = fmaxf(m0, s0);
        m1 = fmaxf(m1, s1);
    }

    float2 wv = reinterpret_cast<const float2*>(w0)[tid];
    float partial = m0 * wv.x + m1 * wv.y;
#pragma unroll
    for (int d = 32; d > 0; d >>= 1) partial += __shfl_down(partial, d, 64);

    __shared__ float red[2];
    if ((tid & 63) == 0) red[tid >> 6] = partial;
    __syncthreads();
    if (tid == 0) {
        float z = red[0] + red[1] + b0[0];
        out[p] = 1.f / (1.f + expf(-z));
    }
}

extern "C" void kernel_launch(void* const* d_in, const int* in_sizes, int n_in,
                              void* d_out, int out_size, void* d_ws, size_t ws_size,
                              hipStream_t stream) {
    const float* x   = (const float*)d_in[0];
    const float* off = (const float*)d_in[1];
    const float* w0  = (const float*)d_in[2];
    const float* b0  = (const float*)d_in[3];
    float* out = (float*)d_out;

    if (ws_size >= XT_BYTES + GEOM_BYTES) {
        // allow 128 KiB dynamic LDS (host-side setting; graph-capture safe)
        (void)hipFuncSetAttribute((const void*)deform_tiled_kernel,
                                  hipFuncAttributeMaxDynamicSharedMemorySize,
                                  HALO_BYTES);
        ushort* xT = (ushort*)d_ws;
        int4* geom = (int4*)((char*)d_ws + XT_BYTES);
        prep_kernel<<<NT_BLOCKS + NG_BLOCKS, 256, 0, stream>>>(x, xT, off, geom);
        deform_tiled_kernel<<<BB * TPI, 1024, HALO_BYTES, stream>>>(
            (const char*)d_ws, geom, w0, b0, out);
    } else {
        deform_fallback_kernel<<<NPIX, 128, 0, stream>>>(x, off, w0, b0, out);
    }
}

// Round 9
// 76.611 us; speedup vs baseline: 1.3434x; 1.3434x over previous
//
#include <hip/hip_runtime.h>
#include <hip/hip_fp16.h>
#include <math.h>

#define BB 4
#define CC 256
#define HH 100
#define WW 100
#define HWP (HH * WW)
#define NPIX (BB * HWP)

#define CGN 2                    // channel groups
#define CHB 128                  // channels per group
#define ROWB (CHB * 2)           // 256 B per (position, group)

#define XT_BYTES ((size_t)NPIX * CC * 2)       // 20.48 MB, [b][cg][h][w][128] fp16
#define GEOM_BYTES ((size_t)NPIX * 9 * 16)     // 5.76 MB, compact 16B records
#define FEAT_BYTES ((size_t)CGN * NPIX * 4)    // 0.32 MB

#define NT_BLOCKS (BB * HH)                    // 400 transpose blocks
#define NG_BLOCKS ((NPIX + 255) / 256)         // 157 geom blocks

#define TILE 8
#define HALO 16
#define TPD 13
#define TPI (TPD * TPD)                        // 169
#define NBLK (BB * CGN * TPI)                  // 1352 = 8 * 169

#define HALO_LDS (HALO * HALO * ROWB)          // 65536
#define GEOM_LDS (64 * 9 * 16)                 // 9216
#define DYN_LDS (HALO_LDS + GEOM_LDS)          // 74752 -> 2 blocks/CU

// ROCm 7.2 hip_fp16.h lacks __hmax2 — emit v_pk_max_f16 directly.
static __device__ inline uint pk_max_f16(uint a, uint b) {
    uint r;
    asm("v_pk_max_f16 %0, %1, %2" : "=v"(r) : "v"(a), "v"(b));
    return r;
}

// ---------------------------------------------------------------------------
// Prep: blocks [0,400) transpose x[b,c,h,w] f32 -> xTg[b][cg][h][w][128ch] fp16
//       blocks [400,557) compute compact per-(pixel,tap) geometry:
//       int4{ yc0|yc1<<8|xc0<<16|xc1<<24, half2(w00,w01), half2(w10,w11), 0 }
// ---------------------------------------------------------------------------
__global__ __launch_bounds__(256) void prep_kernel(
    const float* __restrict__ x, ushort* __restrict__ xT,
    const float* __restrict__ off, int4* __restrict__ geom) {
    __shared__ uint tileT[WW][CC / 2 + 1];   // 51.6 KB

    if (blockIdx.x < NT_BLOCKS) {
        int bh = blockIdx.x;
        int b = bh / HH;
        int h = bh - b * HH;
        const float* src = x + (size_t)b * CC * HWP + (size_t)h * WW;

        for (int idx = threadIdx.x; idx < (CC / 2) * 25; idx += 256) {
            int c2 = idx / 25;
            int w4 = idx - c2 * 25;
            const float* p0 = src + (size_t)(2 * c2) * HWP + w4 * 4;
            float4 va = *reinterpret_cast<const float4*>(p0);
            float4 vb = *reinterpret_cast<const float4*>(p0 + HWP);
            __half2 h0 = __floats2half2_rn(va.x, vb.x);
            __half2 h1 = __floats2half2_rn(va.y, vb.y);
            __half2 h2 = __floats2half2_rn(va.z, vb.z);
            __half2 h3 = __floats2half2_rn(va.w, vb.w);
            tileT[w4 * 4 + 0][c2] = *reinterpret_cast<uint*>(&h0);
            tileT[w4 * 4 + 1][c2] = *reinterpret_cast<uint*>(&h1);
            tileT[w4 * 4 + 2][c2] = *reinterpret_cast<uint*>(&h2);
            tileT[w4 * 4 + 3][c2] = *reinterpret_cast<uint*>(&h3);
        }
        __syncthreads();

        // write group-major: u2 index = (((b*2+cg)*HH+h)*WW + w)*32 + (c4&31)
        uint2* dstu = reinterpret_cast<uint2*>(xT);
        for (int idx = threadIdx.x; idx < WW * (CC / 4); idx += 256) {
            int w = idx >> 6;
            int c4 = idx & 63;
            int cg = c4 >> 5;
            size_t o = ((size_t)((b * CGN + cg) * HH + h) * WW + w) * 32 + (c4 & 31);
            dstu[o] = make_uint2(tileT[w][2 * c4], tileT[w][2 * c4 + 1]);
        }
        return;
    }

    int p = (blockIdx.x - NT_BLOCKS) * 256 + threadIdx.x;
    if (p >= NPIX) return;
    int b = p / HWP;
    int hw = p - b * HWP;
    int h = hw / WW;
    int w = hw - h * WW;
    const float* offp = off + (size_t)b * 18 * HWP + hw;
#pragma unroll
    for (int k = 0; k < 9; ++k) {
        int kh = k / 3 - 1;
        int kw = k - (k / 3) * 3 - 1;
        float dy = offp[(size_t)(2 * k) * HWP];
        float dx = offp[(size_t)(2 * k + 1) * HWP];
        float py = (float)(h + kh) + dy;
        float px = (float)(w + kw) + dx;
        float y0f = floorf(py), x0f = floorf(px);
        float wy = py - y0f, wx = px - x0f;
        int y0 = (int)y0f, x0 = (int)x0f;
        int y1 = y0 + 1, x1 = x0 + 1;
        bool vy0 = (y0 >= 0) && (y0 < HH);
        bool vy1 = (y1 >= 0) && (y1 < HH);
        bool vx0 = (x0 >= 0) && (x0 < WW);
        bool vx1 = (x1 >= 0) && (x1 < WW);
        int yc0 = min(max(y0, 0), HH - 1);
        int yc1 = min(max(y1, 0), HH - 1);
        int xc0 = min(max(x0, 0), WW - 1);
        int xc1 = min(max(x1, 0), WW - 1);
        float w00 = (1.f - wy) * (1.f - wx) * (float)(vy0 && vx0);
        float w01 = (1.f - wy) * wx * (float)(vy0 && vx1);
        float w10 = wy * (1.f - wx) * (float)(vy1 && vx0);
        float w11 = wy * wx * (float)(vy1 && vx1);
        int packed = yc0 | (yc1 << 8) | (xc0 << 16) | (xc1 << 24);
        __half2 hw01 = __floats2half2_rn(w00, w01);
        __half2 hw23 = __floats2half2_rn(w10, w11);
        geom[(size_t)p * 9 + k] =
            make_int4(packed, *reinterpret_cast<int*>(&hw01),
                      *reinterpret_cast<int*>(&hw23), 0);
    }
}

// ---------------------------------------------------------------------------
// Deform v2: block = 512 threads, 8x8 pixel tile, ONE 128-ch group.
// LDS: 64 KiB halo (16x16 pos x 256 B) + 9 KiB geom tile -> 2 blocks/CU.
// Wave = 2 pixels x 32 ch-quad lanes; per tap: 4 ds_read_b64 (conflict-free
// baseline) + packed fp16 blend/max. Grid 1352 = 8 XCD x 169: XCD k owns one
// (img, ch-group) plane (~5 MB ~= its L2). Out-of-halo taps (~1%) take a
// wave-uniform global fallback. Partials to feat[cg][pix]; combine adds+sigmoid.
// ---------------------------------------------------------------------------
__global__ __launch_bounds__(512) void deform_tiled2_kernel(
    const char* __restrict__ xTg, const int4* __restrict__ geom,
    const float* __restrict__ w0, float* __restrict__ feat) {
    extern __shared__ char lds[];            // halo | geom tile

    // XCD-chunked bijective swizzle: 1352 = 8 * 169
    int lb = (blockIdx.x % 8) * (NBLK / 8) + blockIdx.x / 8;
    int g8 = lb / TPI;                       // 0..7 = (cg, b)
    int tile = lb - g8 * TPI;
    int b = g8 & 3;
    int cg = g8 >> 2;
    int tyi = tile / TPD;
    int ty = tyi * TILE;
    int tx = (tile - tyi * TPD) * TILE;
    int sy = min(max(ty - 4, 0), HH - HALO);
    int sx = min(max(tx - 4, 0), WW - HALO);

    // ---- stage halo: 4096 uint4, 512 threads x 8 iters ----
    {
        const char* hbase =
            xTg + ((size_t)((b * CGN + cg) * HH + sy) * WW + sx) * ROWB;
#pragma unroll
        for (int it = 0; it < 8; ++it) {
            int i = it * 512 + threadIdx.x;  // 0..4095
            int strip = i >> 8;              // y row (256 uint4 = 16px x 256B)
            int within = i & 255;
            uint4 v = *reinterpret_cast<const uint4*>(
                hbase + (size_t)strip * (WW * ROWB) + ((size_t)within << 4));
            *reinterpret_cast<uint4*>(lds + ((size_t)i << 4)) = v;
        }
    }
    // ---- stage geom tile: 576 int4 ----
    {
        int4* gl = reinterpret_cast<int4*>(lds + HALO_LDS);
        for (int i = threadIdx.x; i < 64 * 9; i += 512) {
            int px = i / 9;
            int k = i - px * 9;
            int r = px >> 3, c = px & 7;
            int hh = min(ty + r, HH - 1);
            int ww2 = min(tx + c, WW - 1);
            gl[i] = geom[(size_t)(b * HWP + hh * WW + ww2) * 9 + k];
        }
    }
    __syncthreads();

    int lane = threadIdx.x & 63;
    int wid = threadIdx.x >> 6;              // 0..7
    int half = lane >> 5;                    // which pixel of the pair
    int cl = lane & 31;                      // channel-quad id
    int laneOff = cl << 3;                   // byte offset in 256B row
    float4 wq = reinterpret_cast<const float4*>(w0)[cg * 32 + cl];

#pragma unroll
    for (int pass = 0; pass < 4; ++pass) {
        int pi = pass * 16 + wid * 2 + half; // 0..63
        int r = pi >> 3, c = pi & 7;
        int h = ty + r, w = tx + c;
        bool pvalid = (h < HH) && (w < WW);
        const int4* grec = reinterpret_cast<const int4*>(lds + HALO_LDS) + pi * 9;

        uint m0 = 0xFC00FC00u, m1 = 0xFC00FC00u;
#pragma unroll
        for (int k = 0; k < 9; ++k) {
            int4 rec = grec[k];              // ds_read_b128 broadcast per half
            int packed = rec.x;
            int yc0 = packed & 255, yc1 = (packed >> 8) & 255;
            int xc0 = (packed >> 16) & 255, xc1 = (int)((uint)packed >> 24);
            int ry0 = yc0 - sy, ry1 = yc1 - sy;
            int cx0 = xc0 - sx, cx1 = xc1 - sx;
            bool inh = ((uint)ry0 < (uint)HALO) & ((uint)ry1 < (uint)HALO) &
                       ((uint)cx0 < (uint)HALO) & ((uint)cx1 < (uint)HALO);
            uint2 u00, u01, u10, u11;
            if (__all(inh)) {
                u00 = *reinterpret_cast<const uint2*>(
                    lds + ((((ry0 << 4) + cx0) << 8) + laneOff));
                u01 = *reinterpret_cast<const uint2*>(
                    lds + ((((ry0 << 4) + cx1) << 8) + laneOff));
                u10 = *reinterpret_cast<const uint2*>(
                    lds + ((((ry1 << 4) + cx0) << 8) + laneOff));
                u11 = *reinterpret_cast<const uint2*>(
                    lds + ((((ry1 << 4) + cx1) << 8) + laneOff));
            } else {
                int plane = (b * CGN + cg) * HH;
                u00 = *reinterpret_cast<const uint2*>(
                    xTg + ((size_t)(plane + yc0) * WW + xc0) * ROWB + laneOff);
                u01 = *reinterpret_cast<const uint2*>(
                    xTg + ((size_t)(plane + yc0) * WW + xc1) * ROWB + laneOff);
                u10 = *reinterpret_cast<const uint2*>(
                    xTg + ((size_t)(plane + yc1) * WW + xc0) * ROWB + laneOff);
                u11 = *reinterpret_cast<const uint2*>(
                    xTg + ((size_t)(plane + yc1) * WW + xc1) * ROWB + laneOff);
            }

            uint uwa = (uint)rec.y, uwb = (uint)rec.z;
            uint w00u = (uwa & 0xffffu) | (uwa << 16);
            uint w01u = (uwa >> 16) | (uwa & 0xffff0000u);
            uint w10u = (uwb & 0xffffu) | (uwb << 16);
            uint w11u = (uwb >> 16) | (uwb & 0xffff0000u);
            __half2 w00 = *reinterpret_cast<__half2*>(&w00u);
            __half2 w01 = *reinterpret_cast<__half2*>(&w01u);
            __half2 w10 = *reinterpret_cast<__half2*>(&w10u);
            __half2 w11 = *reinterpret_cast<__half2*>(&w11u);

            __half2 a; uint au;
            au = u00.x; a = *reinterpret_cast<__half2*>(&au);
            __half2 acc0 = __hmul2(a, w00);
            au = u00.y; a = *reinterpret_cast<__half2*>(&au);
            __half2 acc1 = __hmul2(a, w00);
            au = u01.x; a = *reinterpret_cast<__half2*>(&au);
            acc0 = __hfma2(a, w01, acc0);
            au = u01.y; a = *reinterpret_cast<__half2*>(&au);
            acc1 = __hfma2(a, w01, acc1);
            au = u10.x; a = *reinterpret_cast<__half2*>(&au);
            acc0 = __hfma2(a, w10, acc0);
            au = u10.y; a = *reinterpret_cast<__half2*>(&au);
            acc1 = __hfma2(a, w10, acc1);
            au = u11.x; a = *reinterpret_cast<__half2*>(&au);
            acc0 = __hfma2(a, w11, acc0);
            au = u11.y; a = *reinterpret_cast<__half2*>(&au);
            acc1 = __hfma2(a, w11, acc1);

            m0 = pk_max_f16(m0, *reinterpret_cast<uint*>(&acc0));
            m1 = pk_max_f16(m1, *reinterpret_cast<uint*>(&acc1));
        }

        float2 f0 = __half22float2(*reinterpret_cast<__half2*>(&m0));
        float2 f1 = __half22float2(*reinterpret_cast<__half2*>(&m1));
        float part = f0.x * wq.x + f0.y * wq.y + f1.x * wq.z + f1.y * wq.w;
#pragma unroll
        for (int d = 16; d > 0; d >>= 1) part += __shfl_down(part, d, 32);
        if (cl == 0 && pvalid)
            feat[(size_t)cg * NPIX + b * HWP + h * WW + w] = part;
    }
}

// ---------------------------------------------------------------------------
// Combine: out = sigmoid(feat0 + feat1 + bias)
// ---------------------------------------------------------------------------
__global__ __launch_bounds__(256) void combine_kernel(
    const float* __restrict__ feat, const float* __restrict__ b0,
    float* __restrict__ out) {
    int i = blockIdx.x * 256 + threadIdx.x;
    if (i < NPIX) {
        float z = feat[i] + feat[NPIX + i] + b0[0];
        out[i] = 1.f / (1.f + expf(-z));
    }
}

// ---------------------------------------------------------------------------
// Fallback: one block (128 threads) per pixel, f32 path, no workspace needed.
// ---------------------------------------------------------------------------
__global__ __launch_bounds__(128) void deform_fallback_kernel(
    const float* __restrict__ x, const float* __restrict__ off,
    const float* __restrict__ w0, const float* __restrict__ b0,
    float* __restrict__ out) {
    int p = blockIdx.x;
    int b = p / HWP;
    int hw = p - b * HWP;
    int h = hw / WW;
    int w = hw - h * WW;
    int tid = threadIdx.x;

    const float* offp = off + (size_t)b * 18 * HWP + hw;
    const float* xb = x + (size_t)b * CC * HWP + (size_t)(2 * tid) * HWP;

    float m0 = -INFINITY, m1 = -INFINITY;

#pragma unroll
    for (int k = 0; k < 9; ++k) {
        int kh = k / 3 - 1;
        int kw = k - (k / 3) * 3 - 1;
        float dy = offp[(size_t)(2 * k) * HWP];
        float dx = offp[(size_t)(2 * k + 1) * HWP];
        float py = (float)(h + kh) + dy;
        float px = (float)(w + kw) + dx;
        float y0f = floorf(py), x0f = floorf(px);
        float wy = py - y0f, wx = px - x0f;
        int y0 = (int)y0f, x0 = (int)x0f;
        int y1 = y0 + 1, x1 = x0 + 1;
        bool vy0 = (y0 >= 0) && (y0 < HH);
        bool vy1 = (y1 >= 0) && (y1 < HH);
        bool vx0 = (x0 >= 0) && (x0 < WW);
        bool vx1 = (x1 >= 0) && (x1 < WW);
        int yc0 = min(max(y0, 0), HH - 1);
        int yc1 = min(max(y1, 0), HH - 1);
        int xc0 = min(max(x0, 0), WW - 1);
        int xc1 = min(max(x1, 0), WW - 1);
        float w00 = (1.f - wy) * (1.f - wx) * (float)(vy0 && vx0);
        float w01 = (1.f - wy) * wx * (float)(vy0 && vx1);
        float w10 = wy * (1.f - wx) * (float)(vy1 && vx0);
        float w11 = wy * wx * (float)(vy1 && vx1);

        int o00 = yc0 * WW + xc0, o01 = yc0 * WW + xc1;
        int o10 = yc1 * WW + xc0, o11 = yc1 * WW + xc1;
        float s0 = xb[o00] * w00 + xb[o01] * w01 + xb[o10] * w10 + xb[o11] * w11;
        float s1 = xb[o00 + HWP] * w00 + xb[o01 + HWP] * w01 +
                   xb[o10 + HWP] * w10 + xb[o11 + HWP] * w11;
        m0 = fmaxf(m0, s0);
        m1 = fmaxf(m1, s1);
    }

    float2 wv = reinterpret_cast<const float2*>(w0)[tid];
    float partial = m0 * wv.x + m1 * wv.y;
#pragma unroll
    for (int d = 32; d > 0; d >>= 1) partial += __shfl_down(partial, d, 64);

    __shared__ float red[2];
    if ((tid & 63) == 0) red[tid >> 6] = partial;
    __syncthreads();
    if (tid == 0) {
        float z = red[0] + red[1] + b0[0];
        out[p] = 1.f / (1.f + expf(-z));
    }
}

extern "C" void kernel_launch(void* const* d_in, const int* in_sizes, int n_in,
                              void* d_out, int out_size, void* d_ws, size_t ws_size,
                              hipStream_t stream) {
    const float* x   = (const float*)d_in[0];
    const float* off = (const float*)d_in[1];
    const float* w0  = (const float*)d_in[2];
    const float* b0  = (const float*)d_in[3];
    float* out = (float*)d_out;

    if (ws_size >= XT_BYTES + GEOM_BYTES + FEAT_BYTES) {
        (void)hipFuncSetAttribute((const void*)deform_tiled2_kernel,
                                  hipFuncAttributeMaxDynamicSharedMemorySize,
                                  DYN_LDS);
        char* xT = (char*)d_ws;
        int4* geom = (int4*)((char*)d_ws + XT_BYTES);
        float* feat = (float*)((char*)d_ws + XT_BYTES + GEOM_BYTES);
        prep_kernel<<<NT_BLOCKS + NG_BLOCKS, 256, 0, stream>>>(
            x, (ushort*)xT, off, geom);
        deform_tiled2_kernel<<<NBLK, 512, DYN_LDS, stream>>>(
            xT, geom, w0, feat);
        combine_kernel<<<(NPIX + 255) / 256, 256, 0, stream>>>(feat, b0, out);
    } else {
        deform_fallback_kernel<<<NPIX, 128, 0, stream>>>(x, off, w0, b0, out);
    }
}

// Round 10
// 56.484 us; speedup vs baseline: 1.8221x; 1.3563x over previous
//
#include <hip/hip_runtime.h>
#include <hip/hip_fp16.h>
#include <math.h>

#define BB 4
#define CC 256
#define HH 100
#define WW 100
#define HWP (HH * WW)
#define NPIX (BB * HWP)

#define CGN 4                    // channel groups
#define CHB 64                   // channels per group
#define ROWB (CHB * 2)           // 128 B per (position, group)

#define XT_BYTES ((size_t)NPIX * CC * 2)       // 20.48 MB, [b][cg][h][w][64] fp16
#define GEOM_BYTES ((size_t)NPIX * 9 * 16)     // 5.76 MB
#define FEAT_BYTES ((size_t)CGN * NPIX * 4)    // 0.64 MB

#define NT_BLOCKS (BB * HH)                    // 400 transpose blocks
#define NG_BLOCKS ((NPIX + 255) / 256)         // 157 geom blocks

#define TILE 8
#define HALO 16
#define TPD 13
#define TPI (TPD * TPD)                        // 169
#define NBLK (BB * CGN * TPI)                  // 2704 = 8 * 338

// ROCm 7.2 hip_fp16.h lacks __hmax2 — emit v_pk_max_f16 directly.
static __device__ inline uint pk_max_f16(uint a, uint b) {
    uint r;
    asm("v_pk_max_f16 %0, %1, %2" : "=v"(r) : "v"(a), "v"(b));
    return r;
}

// ---------------------------------------------------------------------------
// Prep: blocks [0,400): transpose x[b,c,h,w] f32 -> xTg[b][cg][h][w][64] fp16
//       blocks [400,557): per-(pixel,tap) geometry:
//       int4{ yc0|yc1<<8|xc0<<16|xc1<<24, half2(w00,w01), half2(w10,w11), 0 }
// ---------------------------------------------------------------------------
__global__ __launch_bounds__(256) void prep_kernel(
    const float* __restrict__ x, ushort* __restrict__ xT,
    const float* __restrict__ off, int4* __restrict__ geom) {
    __shared__ uint tileT[WW][CC / 2 + 1];   // 51.6 KB

    if (blockIdx.x < NT_BLOCKS) {
        int bh = blockIdx.x;
        int b = bh / HH;
        int h = bh - b * HH;
        const float* src = x + (size_t)b * CC * HWP + (size_t)h * WW;

        for (int idx = threadIdx.x; idx < (CC / 2) * 25; idx += 256) {
            int c2 = idx / 25;
            int w4 = idx - c2 * 25;
            const float* p0 = src + (size_t)(2 * c2) * HWP + w4 * 4;
            float4 va = *reinterpret_cast<const float4*>(p0);
            float4 vb = *reinterpret_cast<const float4*>(p0 + HWP);
            __half2 h0 = __floats2half2_rn(va.x, vb.x);
            __half2 h1 = __floats2half2_rn(va.y, vb.y);
            __half2 h2 = __floats2half2_rn(va.z, vb.z);
            __half2 h3 = __floats2half2_rn(va.w, vb.w);
            tileT[w4 * 4 + 0][c2] = *reinterpret_cast<uint*>(&h0);
            tileT[w4 * 4 + 1][c2] = *reinterpret_cast<uint*>(&h1);
            tileT[w4 * 4 + 2][c2] = *reinterpret_cast<uint*>(&h2);
            tileT[w4 * 4 + 3][c2] = *reinterpret_cast<uint*>(&h3);
        }
        __syncthreads();

        // write group-major: uint2 idx = (((b*4+cg)*HH+h)*WW + w)*16 + (c4&15)
        uint2* dstu = reinterpret_cast<uint2*>(xT);
        for (int idx = threadIdx.x; idx < WW * (CC / 4); idx += 256) {
            int w = idx >> 6;
            int c4 = idx & 63;
            int cg = c4 >> 4;
            size_t o = ((size_t)((b * CGN + cg) * HH + h) * WW + w) * 16 + (c4 & 15);
            dstu[o] = make_uint2(tileT[w][2 * c4], tileT[w][2 * c4 + 1]);
        }
        return;
    }

    int p = (blockIdx.x - NT_BLOCKS) * 256 + threadIdx.x;
    if (p >= NPIX) return;
    int b = p / HWP;
    int hw = p - b * HWP;
    int h = hw / WW;
    int w = hw - h * WW;
    const float* offp = off + (size_t)b * 18 * HWP + hw;
#pragma unroll
    for (int k = 0; k < 9; ++k) {
        int kh = k / 3 - 1;
        int kw = k - (k / 3) * 3 - 1;
        float dy = offp[(size_t)(2 * k) * HWP];
        float dx = offp[(size_t)(2 * k + 1) * HWP];
        float py = (float)(h + kh) + dy;
        float px = (float)(w + kw) + dx;
        float y0f = floorf(py), x0f = floorf(px);
        float wy = py - y0f, wx = px - x0f;
        int y0 = (int)y0f, x0 = (int)x0f;
        int y1 = y0 + 1, x1 = x0 + 1;
        bool vy0 = (y0 >= 0) && (y0 < HH);
        bool vy1 = (y1 >= 0) && (y1 < HH);
        bool vx0 = (x0 >= 0) && (x0 < WW);
        bool vx1 = (x1 >= 0) && (x1 < WW);
        int yc0 = min(max(y0, 0), HH - 1);
        int yc1 = min(max(y1, 0), HH - 1);
        int xc0 = min(max(x0, 0), WW - 1);
        int xc1 = min(max(x1, 0), WW - 1);
        float w00 = (1.f - wy) * (1.f - wx) * (float)(vy0 && vx0);
        float w01 = (1.f - wy) * wx * (float)(vy0 && vx1);
        float w10 = wy * (1.f - wx) * (float)(vy1 && vx0);
        float w11 = wy * wx * (float)(vy1 && vx1);
        int packed = yc0 | (yc1 << 8) | (xc0 << 16) | (xc1 << 24);
        __half2 hw01 = __floats2half2_rn(w00, w01);
        __half2 hw23 = __floats2half2_rn(w10, w11);
        geom[(size_t)p * 9 + k] =
            make_int4(packed, *reinterpret_cast<int*>(&hw01),
                      *reinterpret_cast<int*>(&hw23), 0);
    }
}

// ---------------------------------------------------------------------------
// Deform v3: block = 512 thr, 8x8 pixel tile, ONE 64-ch group. 32 KiB static
// LDS halo -> 4 blocks/CU (32 waves). Wave = 8 pixels x 8 lanes x 16 B: each
// ds_read_b128 gathers one corner for 8 pixels (per-lane LDS addressing).
// Geom read from L2 per lane. Grid 2704 = 8 XCD x 338; each XCD owns 2
// (b,cg) planes (2.6 MB, L2-resident). Out-of-halo taps: wave-wide global
// fallback. Partials to feat[cg][pix]; combine sums 4 groups + sigmoid.
// ---------------------------------------------------------------------------
__global__ __launch_bounds__(512, 8) void deform_tiled3_kernel(
    const char* __restrict__ xTg, const int4* __restrict__ geom,
    const float* __restrict__ w0, float* __restrict__ feat) {
    __shared__ uint4 halo4[HALO * HALO * 8];   // 32 KiB, row = 8 uint4

    int lb = (blockIdx.x & 7) * (NBLK / 8) + (blockIdx.x >> 3);
    int pl = lb / TPI;                         // 0..15 = (b,cg) plane
    int tile = lb - pl * TPI;
    int b = pl >> 2, cg = pl & 3;
    int tyi = tile / TPD;
    int ty = tyi * TILE;
    int tx = (tile - tyi * TPD) * TILE;
    int sy = min(max(ty - 4, 0), HH - HALO);
    int sx = min(max(tx - 4, 0), WW - HALO);
    int plane = (b * CGN + cg) * HH;

    // ---- stage halo: 2048 uint4 = 32 KiB ----
    const char* hbase = xTg + ((size_t)(plane + sy) * WW + sx) * ROWB;
#pragma unroll
    for (int it = 0; it < 4; ++it) {
        int i = it * 512 + threadIdx.x;        // 0..2047
        int strip = i >> 7;                    // y row: 128 uint4 = 16px*128B
        int within = i & 127;
        halo4[i] = *reinterpret_cast<const uint4*>(
            hbase + (size_t)strip * (WW * ROWB) + ((size_t)within << 4));
    }
    __syncthreads();

    int lane = threadIdx.x & 63;
    int wid = threadIdx.x >> 6;                // tile row 0..7
    int sub = lane >> 3;                       // tile col 0..7
    int cl = lane & 7;                         // 16B channel slot
    int h = ty + wid, wc = tx + sub;
    bool pvalid = (h < HH) && (wc < WW);
    int hh = min(h, HH - 1), wcc = min(wc, WW - 1);
    const int4* grec = geom + (size_t)(b * HWP + hh * WW + wcc) * 9;

    uint m0 = 0xFC00FC00u, m1 = m0, m2 = m0, m3 = m0;

#pragma unroll
    for (int k = 0; k < 9; ++k) {
        int4 rec = grec[k];
        int packed = rec.x;
        int yc0 = packed & 255, yc1 = (packed >> 8) & 255;
        int xc0 = (packed >> 16) & 255, xc1 = (int)((uint)packed >> 24);
        int ry0 = yc0 - sy, ry1 = yc1 - sy;
        int cx0 = xc0 - sx, cx1 = xc1 - sx;
        bool inh = ((uint)ry0 < (uint)HALO) & ((uint)ry1 < (uint)HALO) &
                   ((uint)cx0 < (uint)HALO) & ((uint)cx1 < (uint)HALO);
        uint4 u00, u01, u10, u11;
        if (__all(inh)) {
            u00 = halo4[(((ry0 << 4) + cx0) << 3) + cl];
            u01 = halo4[(((ry0 << 4) + cx1) << 3) + cl];
            u10 = halo4[(((ry1 << 4) + cx0) << 3) + cl];
            u11 = halo4[(((ry1 << 4) + cx1) << 3) + cl];
        } else {
            int lo = cl << 4;
            u00 = *reinterpret_cast<const uint4*>(
                xTg + ((size_t)(plane + yc0) * WW + xc0) * ROWB + lo);
            u01 = *reinterpret_cast<const uint4*>(
                xTg + ((size_t)(plane + yc0) * WW + xc1) * ROWB + lo);
            u10 = *reinterpret_cast<const uint4*>(
                xTg + ((size_t)(plane + yc1) * WW + xc0) * ROWB + lo);
            u11 = *reinterpret_cast<const uint4*>(
                xTg + ((size_t)(plane + yc1) * WW + xc1) * ROWB + lo);
        }

        uint uwa = (uint)rec.y, uwb = (uint)rec.z;
        uint w00u = (uwa & 0xffffu) | (uwa << 16);
        uint w01u = (uwa >> 16) | (uwa & 0xffff0000u);
        uint w10u = (uwb & 0xffffu) | (uwb << 16);
        uint w11u = (uwb >> 16) | (uwb & 0xffff0000u);
        __half2 w00 = *reinterpret_cast<__half2*>(&w00u);
        __half2 w01 = *reinterpret_cast<__half2*>(&w01u);
        __half2 w10 = *reinterpret_cast<__half2*>(&w10u);
        __half2 w11 = *reinterpret_cast<__half2*>(&w11u);

        __half2 a; uint au;
#define BLEND(out, f)                                                     \
        au = u00.f; a = *reinterpret_cast<__half2*>(&au);                 \
        { __half2 acc = __hmul2(a, w00);                                  \
          au = u01.f; a = *reinterpret_cast<__half2*>(&au);               \
          acc = __hfma2(a, w01, acc);                                     \
          au = u10.f; a = *reinterpret_cast<__half2*>(&au);               \
          acc = __hfma2(a, w10, acc);                                     \
          au = u11.f; a = *reinterpret_cast<__half2*>(&au);               \
          acc = __hfma2(a, w11, acc);                                     \
          out = pk_max_f16(out, *reinterpret_cast<uint*>(&acc)); }
        BLEND(m0, x)
        BLEND(m1, y)
        BLEND(m2, z)
        BLEND(m3, w)
#undef BLEND
    }

    // dot with w0: channels cg*64 + cl*8 .. +7
    const float4* wv = reinterpret_cast<const float4*>(w0) + (cg * 16 + cl * 2);
    float4 wq0 = wv[0], wq1 = wv[1];
    float2 f0 = __half22float2(*reinterpret_cast<__half2*>(&m0));
    float2 f1 = __half22float2(*reinterpret_cast<__half2*>(&m1));
    float2 f2 = __half22float2(*reinterpret_cast<__half2*>(&m2));
    float2 f3 = __half22float2(*reinterpret_cast<__half2*>(&m3));
    float part = f0.x * wq0.x + f0.y * wq0.y + f1.x * wq0.z + f1.y * wq0.w +
                 f2.x * wq1.x + f2.y * wq1.y + f3.x * wq1.z + f3.y * wq1.w;
#pragma unroll
    for (int d = 4; d > 0; d >>= 1) part += __shfl_down(part, d, 8);
    if (cl == 0 && pvalid)
        feat[(size_t)cg * NPIX + b * HWP + h * WW + wc] = part;
}

// ---------------------------------------------------------------------------
// Combine: out = sigmoid(sum_cg feat + bias)
// ---------------------------------------------------------------------------
__global__ __launch_bounds__(256) void combine_kernel(
    const float* __restrict__ feat, const float* __restrict__ b0,
    float* __restrict__ out) {
    int i = blockIdx.x * 256 + threadIdx.x;
    if (i < NPIX) {
        float z = feat[i] + feat[NPIX + i] + feat[2 * NPIX + i] +
                  feat[3 * NPIX + i] + b0[0];
        out[i] = 1.f / (1.f + expf(-z));
    }
}

// ---------------------------------------------------------------------------
// Fallback: one block (128 threads) per pixel, f32 path, no workspace needed.
// ---------------------------------------------------------------------------
__global__ __launch_bounds__(128) void deform_fallback_kernel(
    const float* __restrict__ x, const float* __restrict__ off,
    const float* __restrict__ w0, const float* __restrict__ b0,
    float* __restrict__ out) {
    int p = blockIdx.x;
    int b = p / HWP;
    int hw = p - b * HWP;
    int h = hw / WW;
    int w = hw - h * WW;
    int tid = threadIdx.x;

    const float* offp = off + (size_t)b * 18 * HWP + hw;
    const float* xb = x + (size_t)b * CC * HWP + (size_t)(2 * tid) * HWP;

    float m0 = -INFINITY, m1 = -INFINITY;

#pragma unroll
    for (int k = 0; k < 9; ++k) {
        int kh = k / 3 - 1;
        int kw = k - (k / 3) * 3 - 1;
        float dy = offp[(size_t)(2 * k) * HWP];
        float dx = offp[(size_t)(2 * k + 1) * HWP];
        float py = (float)(h + kh) + dy;
        float px = (float)(w + kw) + dx;
        float y0f = floorf(py), x0f = floorf(px);
        float wy = py - y0f, wx = px - x0f;
        int y0 = (int)y0f, x0 = (int)x0f;
        int y1 = y0 + 1, x1 = x0 + 1;
        bool vy0 = (y0 >= 0) && (y0 < HH);
        bool vy1 = (y1 >= 0) && (y1 < HH);
        bool vx0 = (x0 >= 0) && (x0 < WW);
        bool vx1 = (x1 >= 0) && (x1 < WW);
        int yc0 = min(max(y0, 0), HH - 1);
        int yc1 = min(max(y1, 0), HH - 1);
        int xc0 = min(max(x0, 0), WW - 1);
        int xc1 = min(max(x1, 0), WW - 1);
        float w00 = (1.f - wy) * (1.f - wx) * (float)(vy0 && vx0);
        float w01 = (1.f - wy) * wx * (float)(vy0 && vx1);
        float w10 = wy * (1.f - wx) * (float)(vy1 && vx0);
        float w11 = wy * wx * (float)(vy1 && vx1);

        int o00 = yc0 * WW + xc0, o01 = yc0 * WW + xc1;
        int o10 = yc1 * WW + xc0, o11 = yc1 * WW + xc1;
        float s0 = xb[o00] * w00 + xb[o01] * w01 + xb[o10] * w10 + xb[o11] * w11;
        float s1 = xb[o00 + HWP] * w00 + xb[o01 + HWP] * w01 +
                   xb[o10 + HWP] * w10 + xb[o11 + HWP] * w11;
        m0 = fmaxf(m0, s0);
        m1 = fmaxf(m1, s1);
    }

    float2 wv = reinterpret_cast<const float2*>(w0)[tid];
    float partial = m0 * wv.x + m1 * wv.y;
#pragma unroll
    for (int d = 32; d > 0; d >>= 1) partial += __shfl_down(partial, d, 64);

    __shared__ float red[2];
    if ((tid & 63) == 0) red[tid >> 6] = partial;
    __syncthreads();
    if (tid == 0) {
        float z = red[0] + red[1] + b0[0];
        out[p] = 1.f / (1.f + expf(-z));
    }
}

extern "C" void kernel_launch(void* const* d_in, const int* in_sizes, int n_in,
                              void* d_out, int out_size, void* d_ws, size_t ws_size,
                              hipStream_t stream) {
    const float* x   = (const float*)d_in[0];
    const float* off = (const float*)d_in[1];
    const float* w0  = (const float*)d_in[2];
    const float* b0  = (const float*)d_in[3];
    float* out = (float*)d_out;

    if (ws_size >= XT_BYTES + GEOM_BYTES + FEAT_BYTES) {
        char* xT = (char*)d_ws;
        int4* geom = (int4*)((char*)d_ws + XT_BYTES);
        float* feat = (float*)((char*)d_ws + XT_BYTES + GEOM_BYTES);
        prep_kernel<<<NT_BLOCKS + NG_BLOCKS, 256, 0, stream>>>(
            x, (ushort*)xT, off, geom);
        deform_tiled3_kernel<<<NBLK, 512, 0, stream>>>(xT, geom, w0, feat);
        combine_kernel<<<(NPIX + 255) / 256, 256, 0, stream>>>(feat, b0, out);
    } else {
        deform_fallback_kernel<<<NPIX, 128, 0, stream>>>(x, off, w0, b0, out);
    }
}

// Round 11
// 52.306 us; speedup vs baseline: 1.9676x; 1.0799x over previous
//
#include <hip/hip_runtime.h>
#include <hip/hip_fp16.h>
#include <math.h>

#define BB 4
#define CC 256
#define HH 100
#define WW 100
#define HWP (HH * WW)
#define NPIX (BB * HWP)

#define CGN 4                    // channel groups
#define CHB 64                   // channels per group
#define ROWB (CHB * 2)           // 128 B per (position, group)

#define XT_BYTES ((size_t)NPIX * CC * 2)       // 20.48 MB, [b][cg][h][w][64] fp16
#define GEOM_BYTES ((size_t)NPIX * 9 * 16)     // 5.76 MB
#define FEAT_BYTES ((size_t)CGN * NPIX * 4)    // 0.64 MB

#define NT_BLOCKS (BB * HH)                    // 400 transpose blocks
#define NG_BLOCKS ((NPIX + 255) / 256)         // 157 geom blocks

#define TILE 8
#define HALO 16
#define TPD 13
#define TPI (TPD * TPD)                        // 169
#define NBLK (BB * CGN * TPI)                  // 2704 = 8 * 338

// ROCm 7.2 hip_fp16.h lacks __hmax2 — emit v_pk_max_f16 directly.
static __device__ inline uint pk_max_f16(uint a, uint b) {
    uint r;
    asm("v_pk_max_f16 %0, %1, %2" : "=v"(r) : "v"(a), "v"(b));
    return r;
}

// ---------------------------------------------------------------------------
// Prep: blocks [0,400): transpose x[b,c,h,w] f32 -> xTg[b][cg][h][w][64] fp16
//       blocks [400,557): per-(pixel,tap) geometry:
//       int4{ yc0|yc1<<8|xc0<<16|xc1<<24, half2(w00,w01), half2(w10,w11), 0 }
// ---------------------------------------------------------------------------
__global__ __launch_bounds__(256) void prep_kernel(
    const float* __restrict__ x, ushort* __restrict__ xT,
    const float* __restrict__ off, int4* __restrict__ geom) {
    __shared__ uint tileT[WW][CC / 2 + 1];   // 51.6 KB

    if (blockIdx.x < NT_BLOCKS) {
        int bh = blockIdx.x;
        int b = bh / HH;
        int h = bh - b * HH;
        const float* src = x + (size_t)b * CC * HWP + (size_t)h * WW;

        for (int idx = threadIdx.x; idx < (CC / 2) * 25; idx += 256) {
            int c2 = idx / 25;
            int w4 = idx - c2 * 25;
            const float* p0 = src + (size_t)(2 * c2) * HWP + w4 * 4;
            float4 va = *reinterpret_cast<const float4*>(p0);
            float4 vb = *reinterpret_cast<const float4*>(p0 + HWP);
            __half2 h0 = __floats2half2_rn(va.x, vb.x);
            __half2 h1 = __floats2half2_rn(va.y, vb.y);
            __half2 h2 = __floats2half2_rn(va.z, vb.z);
            __half2 h3 = __floats2half2_rn(va.w, vb.w);
            tileT[w4 * 4 + 0][c2] = *reinterpret_cast<uint*>(&h0);
            tileT[w4 * 4 + 1][c2] = *reinterpret_cast<uint*>(&h1);
            tileT[w4 * 4 + 2][c2] = *reinterpret_cast<uint*>(&h2);
            tileT[w4 * 4 + 3][c2] = *reinterpret_cast<uint*>(&h3);
        }
        __syncthreads();

        // write group-major: uint2 idx = (((b*4+cg)*HH+h)*WW + w)*16 + (c4&15)
        uint2* dstu = reinterpret_cast<uint2*>(xT);
        for (int idx = threadIdx.x; idx < WW * (CC / 4); idx += 256) {
            int w = idx >> 6;
            int c4 = idx & 63;
            int cg = c4 >> 4;
            size_t o = ((size_t)((b * CGN + cg) * HH + h) * WW + w) * 16 + (c4 & 15);
            dstu[o] = make_uint2(tileT[w][2 * c4], tileT[w][2 * c4 + 1]);
        }
        return;
    }

    int p = (blockIdx.x - NT_BLOCKS) * 256 + threadIdx.x;
    if (p >= NPIX) return;
    int b = p / HWP;
    int hw = p - b * HWP;
    int h = hw / WW;
    int w = hw - h * WW;
    const float* offp = off + (size_t)b * 18 * HWP + hw;
#pragma unroll
    for (int k = 0; k < 9; ++k) {
        int kh = k / 3 - 1;
        int kw = k - (k / 3) * 3 - 1;
        float dy = offp[(size_t)(2 * k) * HWP];
        float dx = offp[(size_t)(2 * k + 1) * HWP];
        float py = (float)(h + kh) + dy;
        float px = (float)(w + kw) + dx;
        float y0f = floorf(py), x0f = floorf(px);
        float wy = py - y0f, wx = px - x0f;
        int y0 = (int)y0f, x0 = (int)x0f;
        int y1 = y0 + 1, x1 = x0 + 1;
        bool vy0 = (y0 >= 0) && (y0 < HH);
        bool vy1 = (y1 >= 0) && (y1 < HH);
        bool vx0 = (x0 >= 0) && (x0 < WW);
        bool vx1 = (x1 >= 0) && (x1 < WW);
        int yc0 = min(max(y0, 0), HH - 1);
        int yc1 = min(max(y1, 0), HH - 1);
        int xc0 = min(max(x0, 0), WW - 1);
        int xc1 = min(max(x1, 0), WW - 1);
        float w00 = (1.f - wy) * (1.f - wx) * (float)(vy0 && vx0);
        float w01 = (1.f - wy) * wx * (float)(vy0 && vx1);
        float w10 = wy * (1.f - wx) * (float)(vy1 && vx0);
        float w11 = wy * wx * (float)(vy1 && vx1);
        int packed = yc0 | (yc1 << 8) | (xc0 << 16) | (xc1 << 24);
        __half2 hw01 = __floats2half2_rn(w00, w01);
        __half2 hw23 = __floats2half2_rn(w10, w11);
        geom[(size_t)p * 9 + k] =
            make_int4(packed, *reinterpret_cast<int*>(&hw01),
                      *reinterpret_cast<int*>(&hw23), 0);
    }
}

// ---------------------------------------------------------------------------
// Deform v4: block = 512 thr, 8x8 pixel tile, ONE 64-ch group.
// R10 lesson: halo row = 128 B put all 8 pixel-subgroups on bank-quad cl*4
// -> 8-way conflict ~ the whole kernel cost. Fix: XOR bank swizzle
// slot = cl ^ (cx&7) on store and load. Also stage the 9 KB geom tile in
// LDS (conflict-free broadcast) to kill per-tap L2 latency. 41 KB LDS ->
// 3 blocks/CU. Out-of-halo taps: wave-uniform global fallback.
// ---------------------------------------------------------------------------
__global__ __launch_bounds__(512, 6) void deform_tiled4_kernel(
    const char* __restrict__ xTg, const int4* __restrict__ geom,
    const float* __restrict__ w0, float* __restrict__ feat) {
    __shared__ uint4 halo4[HALO * HALO * 8];   // 32 KiB
    __shared__ int4 geomL[TILE * TILE * 9];    // 9 KiB

    int lb = (blockIdx.x & 7) * (NBLK / 8) + (blockIdx.x >> 3);
    int pl = lb / TPI;                         // 0..15 = (b,cg) plane
    int tile = lb - pl * TPI;
    int b = pl >> 2, cg = pl & 3;
    int tyi = tile / TPD;
    int ty = tyi * TILE;
    int tx = (tile - tyi * TPD) * TILE;
    int sy = min(max(ty - 4, 0), HH - HALO);
    int sx = min(max(tx - 4, 0), WW - HALO);
    int plane = (b * CGN + cg) * HH;

    // ---- stage halo (bank-swizzled) + geom tile ----
    const char* hbase = xTg + ((size_t)(plane + sy) * WW + sx) * ROWB;
#pragma unroll
    for (int it = 0; it < 4; ++it) {
        int i = it * 512 + threadIdx.x;        // 0..2047
        int strip = i >> 7;                    // 16 positions x 8 slots
        int within = i & 127;
        uint4 v = *reinterpret_cast<const uint4*>(
            hbase + (size_t)strip * (WW * ROWB) + ((size_t)within << 4));
        int pos = (strip << 4) + (within >> 3);
        int c = within & 7;
        halo4[(pos << 3) + (c ^ (pos & 7))] = v;
    }
    for (int i = threadIdx.x; i < TILE * TILE * 9; i += 512) {
        int px = i / 9;
        int k = i - px * 9;
        int r = px >> 3, c = px & 7;
        int hh2 = min(ty + r, HH - 1);
        int ww2 = min(tx + c, WW - 1);
        geomL[i] = geom[(size_t)(b * HWP + hh2 * WW + ww2) * 9 + k];
    }
    __syncthreads();

    int lane = threadIdx.x & 63;
    int wid = threadIdx.x >> 6;                // tile row 0..7
    int sub = lane >> 3;                       // tile col 0..7
    int cl = lane & 7;                         // 16B channel slot
    int h = ty + wid, wc = tx + sub;
    bool pvalid = (h < HH) && (wc < WW);
    int pi = wid * 8 + sub;

    uint m0 = 0xFC00FC00u, m1 = m0, m2 = m0, m3 = m0;

#pragma unroll
    for (int k = 0; k < 9; ++k) {
        int4 rec = geomL[pi * 9 + k];
        int packed = rec.x;
        int yc0 = packed & 255, yc1 = (packed >> 8) & 255;
        int xc0 = (packed >> 16) & 255, xc1 = (int)((uint)packed >> 24);
        int ry0 = yc0 - sy, ry1 = yc1 - sy;
        int cx0 = xc0 - sx, cx1 = xc1 - sx;
        bool inh = ((uint)ry0 < (uint)HALO) & ((uint)ry1 < (uint)HALO) &
                   ((uint)cx0 < (uint)HALO) & ((uint)cx1 < (uint)HALO);
        uint4 u00, u01, u10, u11;
        if (__all(inh)) {
            int p00 = (ry0 << 4) + cx0, p01 = (ry0 << 4) + cx1;
            int p10 = (ry1 << 4) + cx0, p11 = (ry1 << 4) + cx1;
            u00 = halo4[(p00 << 3) + (cl ^ (cx0 & 7))];
            u01 = halo4[(p01 << 3) + (cl ^ (cx1 & 7))];
            u10 = halo4[(p10 << 3) + (cl ^ (cx0 & 7))];
            u11 = halo4[(p11 << 3) + (cl ^ (cx1 & 7))];
        } else {
            int lo = cl << 4;
            u00 = *reinterpret_cast<const uint4*>(
                xTg + ((size_t)(plane + yc0) * WW + xc0) * ROWB + lo);
            u01 = *reinterpret_cast<const uint4*>(
                xTg + ((size_t)(plane + yc0) * WW + xc1) * ROWB + lo);
            u10 = *reinterpret_cast<const uint4*>(
                xTg + ((size_t)(plane + yc1) * WW + xc0) * ROWB + lo);
            u11 = *reinterpret_cast<const uint4*>(
                xTg + ((size_t)(plane + yc1) * WW + xc1) * ROWB + lo);
        }

        uint uwa = (uint)rec.y, uwb = (uint)rec.z;
        uint w00u = (uwa & 0xffffu) | (uwa << 16);
        uint w01u = (uwa >> 16) | (uwa & 0xffff0000u);
        uint w10u = (uwb & 0xffffu) | (uwb << 16);
        uint w11u = (uwb >> 16) | (uwb & 0xffff0000u);
        __half2 w00 = *reinterpret_cast<__half2*>(&w00u);
        __half2 w01 = *reinterpret_cast<__half2*>(&w01u);
        __half2 w10 = *reinterpret_cast<__half2*>(&w10u);
        __half2 w11 = *reinterpret_cast<__half2*>(&w11u);

        __half2 a; uint au;
#define BLEND(out, f)                                                     \
        au = u00.f; a = *reinterpret_cast<__half2*>(&au);                 \
        { __half2 acc = __hmul2(a, w00);                                  \
          au = u01.f; a = *reinterpret_cast<__half2*>(&au);               \
          acc = __hfma2(a, w01, acc);                                     \
          au = u10.f; a = *reinterpret_cast<__half2*>(&au);               \
          acc = __hfma2(a, w10, acc);                                     \
          au = u11.f; a = *reinterpret_cast<__half2*>(&au);               \
          acc = __hfma2(a, w11, acc);                                     \
          out = pk_max_f16(out, *reinterpret_cast<uint*>(&acc)); }
        BLEND(m0, x)
        BLEND(m1, y)
        BLEND(m2, z)
        BLEND(m3, w)
#undef BLEND
    }

    // dot with w0: channels cg*64 + cl*8 .. +7
    const float4* wv = reinterpret_cast<const float4*>(w0) + (cg * 16 + cl * 2);
    float4 wq0 = wv[0], wq1 = wv[1];
    float2 f0 = __half22float2(*reinterpret_cast<__half2*>(&m0));
    float2 f1 = __half22float2(*reinterpret_cast<__half2*>(&m1));
    float2 f2 = __half22float2(*reinterpret_cast<__half2*>(&m2));
    float2 f3 = __half22float2(*reinterpret_cast<__half2*>(&m3));
    float part = f0.x * wq0.x + f0.y * wq0.y + f1.x * wq0.z + f1.y * wq0.w +
                 f2.x * wq1.x + f2.y * wq1.y + f3.x * wq1.z + f3.y * wq1.w;
#pragma unroll
    for (int d = 4; d > 0; d >>= 1) part += __shfl_down(part, d, 8);
    if (cl == 0 && pvalid)
        feat[(size_t)cg * NPIX + b * HWP + h * WW + wc] = part;
}

// ---------------------------------------------------------------------------
// Combine: out = sigmoid(sum_cg feat + bias)
// ---------------------------------------------------------------------------
__global__ __launch_bounds__(256) void combine_kernel(
    const float* __restrict__ feat, const float* __restrict__ b0,
    float* __restrict__ out) {
    int i = blockIdx.x * 256 + threadIdx.x;
    if (i < NPIX) {
        float z = feat[i] + feat[NPIX + i] + feat[2 * NPIX + i] +
                  feat[3 * NPIX + i] + b0[0];
        out[i] = 1.f / (1.f + expf(-z));
    }
}

// ---------------------------------------------------------------------------
// Fallback: one block (128 threads) per pixel, f32 path, no workspace needed.
// ---------------------------------------------------------------------------
__global__ __launch_bounds__(128) void deform_fallback_kernel(
    const float* __restrict__ x, const float* __restrict__ off,
    const float* __restrict__ w0, const float* __restrict__ b0,
    float* __restrict__ out) {
    int p = blockIdx.x;
    int b = p / HWP;
    int hw = p - b * HWP;
    int h = hw / WW;
    int w = hw - h * WW;
    int tid = threadIdx.x;

    const float* offp = off + (size_t)b * 18 * HWP + hw;
    const float* xb = x + (size_t)b * CC * HWP + (size_t)(2 * tid) * HWP;

    float m0 = -INFINITY, m1 = -INFINITY;

#pragma unroll
    for (int k = 0; k < 9; ++k) {
        int kh = k / 3 - 1;
        int kw = k - (k / 3) * 3 - 1;
        float dy = offp[(size_t)(2 * k) * HWP];
        float dx = offp[(size_t)(2 * k + 1) * HWP];
        float py = (float)(h + kh) + dy;
        float px = (float)(w + kw) + dx;
        float y0f = floorf(py), x0f = floorf(px);
        float wy = py - y0f, wx = px - x0f;
        int y0 = (int)y0f, x0 = (int)x0f;
        int y1 = y0 + 1, x1 = x0 + 1;
        bool vy0 = (y0 >= 0) && (y0 < HH);
        bool vy1 = (y1 >= 0) && (y1 < HH);
        bool vx0 = (x0 >= 0) && (x0 < WW);
        bool vx1 = (x1 >= 0) && (x1 < WW);
        int yc0 = min(max(y0, 0), HH - 1);
        int yc1 = min(max(y1, 0), HH - 1);
        int xc0 = min(max(x0, 0), WW - 1);
        int xc1 = min(max(x1, 0), WW - 1);
        float w00 = (1.f - wy) * (1.f - wx) * (float)(vy0 && vx0);
        float w01 = (1.f - wy) * wx * (float)(vy0 && vx1);
        float w10 = wy * (1.f - wx) * (float)(vy1 && vx0);
        float w11 = wy * wx * (float)(vy1 && vx1);

        int o00 = yc0 * WW + xc0, o01 = yc0 * WW + xc1;
        int o10 = yc1 * WW + xc0, o11 = yc1 * WW + xc1;
        float s0 = xb[o00] * w00 + xb[o01] * w01 + xb[o10] * w10 + xb[o11] * w11;
        float s1 = xb[o00 + HWP] * w00 + xb[o01 + HWP] * w01 +
                   xb[o10 + HWP] * w10 + xb[o11 + HWP] * w11;
        m0 = fmaxf(m0, s0);
        m1 = fmaxf(m1, s1);
    }

    float2 wv = reinterpret_cast<const float2*>(w0)[tid];
    float partial = m0 * wv.x + m1 * wv.y;
#pragma unroll
    for (int d = 32; d > 0; d >>= 1) partial += __shfl_down(partial, d, 64);

    __shared__ float red[2];
    if ((tid & 63) == 0) red[tid >> 6] = partial;
    __syncthreads();
    if (tid == 0) {
        float z = red[0] + red[1] + b0[0];
        out[p] = 1.f / (1.f + expf(-z));
    }
}

extern "C" void kernel_launch(void* const* d_in, const int* in_sizes, int n_in,
                              void* d_out, int out_size, void* d_ws, size_t ws_size,
                              hipStream_t stream) {
    const float* x   = (const float*)d_in[0];
    const float* off = (const float*)d_in[1];
    const float* w0  = (const float*)d_in[2];
    const float* b0  = (const float*)d_in[3];
    float* out = (float*)d_out;

    if (ws_size >= XT_BYTES + GEOM_BYTES + FEAT_BYTES) {
        char* xT = (char*)d_ws;
        int4* geom = (int4*)((char*)d_ws + XT_BYTES);
        float* feat = (float*)((char*)d_ws + XT_BYTES + GEOM_BYTES);
        prep_kernel<<<NT_BLOCKS + NG_BLOCKS, 256, 0, stream>>>(
            x, (ushort*)xT, off, geom);
        deform_tiled4_kernel<<<NBLK, 512, 0, stream>>>(xT, geom, w0, feat);
        combine_kernel<<<(NPIX + 255) / 256, 256, 0, stream>>>(feat, b0, out);
    } else {
        deform_fallback_kernel<<<NPIX, 128, 0, stream>>>(x, off, w0, b0, out);
    }
}

// Round 12
// 44.777 us; speedup vs baseline: 2.2984x; 1.1681x over previous
//
#include <hip/hip_runtime.h>
#include <hip/hip_fp16.h>
#include <math.h>

#define BB 4
#define CC 256
#define HH 100
#define WW 100
#define HWP (HH * WW)
#define NPIX (BB * HWP)

#define CGN 4                    // channel groups
#define CHB 64                   // channels per group
#define ROWB (CHB * 2)           // 128 B per (position, group)

#define XT_BYTES ((size_t)NPIX * CC * 2)       // 20.48 MB, [b][cg][h][w][64] fp16
#define FEAT_BYTES ((size_t)CGN * NPIX * 4)    // 0.64 MB

#define NT_BLOCKS (BB * HH)                    // 400 transpose blocks

#define TILE 8
#define HALO 16
#define TPD 13
#define TPI (TPD * TPD)                        // 169
#define NBLK (BB * CGN * TPI)                  // 2704 = 8 * 338

#define KGSPLIT 6                              // taps >= this go via global/L2

// ROCm 7.2 hip_fp16.h lacks __hmax2 — emit v_pk_max_f16 directly.
static __device__ inline uint pk_max_f16(uint a, uint b) {
    uint r;
    asm("v_pk_max_f16 %0, %1, %2" : "=v"(r) : "v"(a), "v"(b));
    return r;
}

// ---------------------------------------------------------------------------
// Prep (transpose only now): x[b,c,h,w] f32 -> xTg[b][cg][h][w][64] fp16.
// ---------------------------------------------------------------------------
__global__ __launch_bounds__(256) void prep_kernel(
    const float* __restrict__ x, ushort* __restrict__ xT) {
    __shared__ uint tileT[WW][CC / 2 + 1];   // 51.6 KB
    int bh = blockIdx.x;
    int b = bh / HH;
    int h = bh - b * HH;
    const float* src = x + (size_t)b * CC * HWP + (size_t)h * WW;

    for (int idx = threadIdx.x; idx < (CC / 2) * 25; idx += 256) {
        int c2 = idx / 25;
        int w4 = idx - c2 * 25;
        const float* p0 = src + (size_t)(2 * c2) * HWP + w4 * 4;
        float4 va = *reinterpret_cast<const float4*>(p0);
        float4 vb = *reinterpret_cast<const float4*>(p0 + HWP);
        __half2 h0 = __floats2half2_rn(va.x, vb.x);
        __half2 h1 = __floats2half2_rn(va.y, vb.y);
        __half2 h2 = __floats2half2_rn(va.z, vb.z);
        __half2 h3 = __floats2half2_rn(va.w, vb.w);
        tileT[w4 * 4 + 0][c2] = *reinterpret_cast<uint*>(&h0);
        tileT[w4 * 4 + 1][c2] = *reinterpret_cast<uint*>(&h1);
        tileT[w4 * 4 + 2][c2] = *reinterpret_cast<uint*>(&h2);
        tileT[w4 * 4 + 3][c2] = *reinterpret_cast<uint*>(&h3);
    }
    __syncthreads();

    // write group-major: uint2 idx = (((b*4+cg)*HH+h)*WW + w)*16 + (c4&15)
    uint2* dstu = reinterpret_cast<uint2*>(xT);
    for (int idx = threadIdx.x; idx < WW * (CC / 4); idx += 256) {
        int w = idx >> 6;
        int c4 = idx & 63;
        int cg = c4 >> 4;
        size_t o = ((size_t)((b * CGN + cg) * HH + h) * WW + w) * 16 + (c4 & 15);
        dstu[o] = make_uint2(tileT[w][2 * c4], tileT[w][2 * c4 + 1]);
    }
}

// ---------------------------------------------------------------------------
// Deform v5: block = 512 thr, 8x8 pixel tile, ONE 64-ch group.
// R11 lesson: DS pipe carried ALL 45 b128/wave (~20us) while the vector-mem
// path idled. Hybrid: taps 0..5 from the 32KB bank-swizzled LDS halo, taps
// 6..8 straight from the (L2-resident) global plane -> the two pipes overlap.
// Geometry (64px x 9 taps) is computed in-kernel into LDS from `off` (drops
// the geom global buffer + extra prep pass entirely).
// ---------------------------------------------------------------------------
__global__ __launch_bounds__(512, 6) void deform_tiled5_kernel(
    const char* __restrict__ xTg, const float* __restrict__ off,
    const float* __restrict__ w0, float* __restrict__ feat) {
    __shared__ uint4 halo4[HALO * HALO * 8];   // 32 KiB
    __shared__ int4 geomL[TILE * TILE * 9];    // 9 KiB, idx = px*9+k

    int lb = (blockIdx.x & 7) * (NBLK / 8) + (blockIdx.x >> 3);
    int pl = lb / TPI;                         // 0..15 = (b,cg) plane
    int tile = lb - pl * TPI;
    int b = pl >> 2, cg = pl & 3;
    int tyi = tile / TPD;
    int ty = tyi * TILE;
    int tx = (tile - tyi * TPD) * TILE;
    int sy = min(max(ty - 4, 0), HH - HALO);
    int sx = min(max(tx - 4, 0), WW - HALO);
    int plane = (b * CGN + cg) * HH;

    // ---- stage halo (bank-swizzled) ----
    const char* hbase = xTg + ((size_t)(plane + sy) * WW + sx) * ROWB;
#pragma unroll
    for (int it = 0; it < 4; ++it) {
        int i = it * 512 + threadIdx.x;        // 0..2047
        int strip = i >> 7;
        int within = i & 127;
        uint4 v = *reinterpret_cast<const uint4*>(
            hbase + (size_t)strip * (WW * ROWB) + ((size_t)within << 4));
        int pos = (strip << 4) + (within >> 3);
        int c = within & 7;
        halo4[(pos << 3) + (c ^ (pos & 7))] = v;
    }
    // ---- compute geometry tile in-kernel: i = k*64 + px ----
    {
        const float* offb = off + (size_t)b * 18 * HWP;
        for (int i = threadIdx.x; i < 9 * 64; i += 512) {
            int k = i >> 6;
            int px = i & 63;
            int r = px >> 3, c = px & 7;
            int h2 = min(ty + r, HH - 1);
            int w2 = min(tx + c, WW - 1);
            int hw = h2 * WW + w2;
            float dy = offb[(size_t)(2 * k) * HWP + hw];
            float dx = offb[(size_t)(2 * k + 1) * HWP + hw];
            int kh = k / 3 - 1;
            int kw = k - (k / 3) * 3 - 1;
            float py = (float)(h2 + kh) + dy;
            float px_ = (float)(w2 + kw) + dx;
            float y0f = floorf(py), x0f = floorf(px_);
            float wy = py - y0f, wx = px_ - x0f;
            int y0 = (int)y0f, x0 = (int)x0f;
            int y1 = y0 + 1, x1 = x0 + 1;
            bool vy0 = (y0 >= 0) && (y0 < HH);
            bool vy1 = (y1 >= 0) && (y1 < HH);
            bool vx0 = (x0 >= 0) && (x0 < WW);
            bool vx1 = (x1 >= 0) && (x1 < WW);
            int yc0 = min(max(y0, 0), HH - 1);
            int yc1 = min(max(y1, 0), HH - 1);
            int xc0 = min(max(x0, 0), WW - 1);
            int xc1 = min(max(x1, 0), WW - 1);
            float w00 = (1.f - wy) * (1.f - wx) * (float)(vy0 && vx0);
            float w01 = (1.f - wy) * wx * (float)(vy0 && vx1);
            float w10 = wy * (1.f - wx) * (float)(vy1 && vx0);
            float w11 = wy * wx * (float)(vy1 && vx1);
            int packed = yc0 | (yc1 << 8) | (xc0 << 16) | (xc1 << 24);
            __half2 hw01 = __floats2half2_rn(w00, w01);
            __half2 hw23 = __floats2half2_rn(w10, w11);
            geomL[px * 9 + k] =
                make_int4(packed, *reinterpret_cast<int*>(&hw01),
                          *reinterpret_cast<int*>(&hw23), 0);
        }
    }
    __syncthreads();

    int lane = threadIdx.x & 63;
    int wid = threadIdx.x >> 6;                // tile row 0..7
    int sub = lane >> 3;                       // tile col 0..7
    int cl = lane & 7;                         // 16B channel slot
    int h = ty + wid, wc = tx + sub;
    bool pvalid = (h < HH) && (wc < WW);
    int pi = wid * 8 + sub;
    int lo = cl << 4;

    uint m0 = 0xFC00FC00u, m1 = m0, m2 = m0, m3 = m0;

#pragma unroll
    for (int k = 0; k < 9; ++k) {
        int4 rec = geomL[pi * 9 + k];
        int packed = rec.x;
        int yc0 = packed & 255, yc1 = (packed >> 8) & 255;
        int xc0 = (packed >> 16) & 255, xc1 = (int)((uint)packed >> 24);
        uint4 u00, u01, u10, u11;
        bool useLds = false;
        if (k < KGSPLIT) {
            int ry0 = yc0 - sy, ry1 = yc1 - sy;
            int cx0 = xc0 - sx, cx1 = xc1 - sx;
            bool inh = ((uint)ry0 < (uint)HALO) & ((uint)ry1 < (uint)HALO) &
                       ((uint)cx0 < (uint)HALO) & ((uint)cx1 < (uint)HALO);
            useLds = __all(inh);
            if (useLds) {
                int p00 = (ry0 << 4) + cx0, p01 = (ry0 << 4) + cx1;
                int p10 = (ry1 << 4) + cx0, p11 = (ry1 << 4) + cx1;
                u00 = halo4[(p00 << 3) + (cl ^ (cx0 & 7))];
                u01 = halo4[(p01 << 3) + (cl ^ (cx1 & 7))];
                u10 = halo4[(p10 << 3) + (cl ^ (cx0 & 7))];
                u11 = halo4[(p11 << 3) + (cl ^ (cx1 & 7))];
            }
        }
        if (!useLds) {
            u00 = *reinterpret_cast<const uint4*>(
                xTg + ((size_t)(plane + yc0) * WW + xc0) * ROWB + lo);
            u01 = *reinterpret_cast<const uint4*>(
                xTg + ((size_t)(plane + yc0) * WW + xc1) * ROWB + lo);
            u10 = *reinterpret_cast<const uint4*>(
                xTg + ((size_t)(plane + yc1) * WW + xc0) * ROWB + lo);
            u11 = *reinterpret_cast<const uint4*>(
                xTg + ((size_t)(plane + yc1) * WW + xc1) * ROWB + lo);
        }

        uint uwa = (uint)rec.y, uwb = (uint)rec.z;
        uint w00u = (uwa & 0xffffu) | (uwa << 16);
        uint w01u = (uwa >> 16) | (uwa & 0xffff0000u);
        uint w10u = (uwb & 0xffffu) | (uwb << 16);
        uint w11u = (uwb >> 16) | (uwb & 0xffff0000u);
        __half2 w00 = *reinterpret_cast<__half2*>(&w00u);
        __half2 w01 = *reinterpret_cast<__half2*>(&w01u);
        __half2 w10 = *reinterpret_cast<__half2*>(&w10u);
        __half2 w11 = *reinterpret_cast<__half2*>(&w11u);

        __half2 a; uint au;
#define BLEND(out, f)                                                     \
        au = u00.f; a = *reinterpret_cast<__half2*>(&au);                 \
        { __half2 acc = __hmul2(a, w00);                                  \
          au = u01.f; a = *reinterpret_cast<__half2*>(&au);               \
          acc = __hfma2(a, w01, acc);                                     \
          au = u10.f; a = *reinterpret_cast<__half2*>(&au);               \
          acc = __hfma2(a, w10, acc);                                     \
          au = u11.f; a = *reinterpret_cast<__half2*>(&au);               \
          acc = __hfma2(a, w11, acc);                                     \
          out = pk_max_f16(out, *reinterpret_cast<uint*>(&acc)); }
        BLEND(m0, x)
        BLEND(m1, y)
        BLEND(m2, z)
        BLEND(m3, w)
#undef BLEND
    }

    // dot with w0: channels cg*64 + cl*8 .. +7
    const float4* wv = reinterpret_cast<const float4*>(w0) + (cg * 16 + cl * 2);
    float4 wq0 = wv[0], wq1 = wv[1];
    float2 f0 = __half22float2(*reinterpret_cast<__half2*>(&m0));
    float2 f1 = __half22float2(*reinterpret_cast<__half2*>(&m1));
    float2 f2 = __half22float2(*reinterpret_cast<__half2*>(&m2));
    float2 f3 = __half22float2(*reinterpret_cast<__half2*>(&m3));
    float part = f0.x * wq0.x + f0.y * wq0.y + f1.x * wq0.z + f1.y * wq0.w +
                 f2.x * wq1.x + f2.y * wq1.y + f3.x * wq1.z + f3.y * wq1.w;
#pragma unroll
    for (int d = 4; d > 0; d >>= 1) part += __shfl_down(part, d, 8);
    if (cl == 0 && pvalid)
        feat[(size_t)cg * NPIX + b * HWP + h * WW + wc] = part;
}

// ---------------------------------------------------------------------------
// Combine: out = sigmoid(sum_cg feat + bias)
// ---------------------------------------------------------------------------
__global__ __launch_bounds__(256) void combine_kernel(
    const float* __restrict__ feat, const float* __restrict__ b0,
    float* __restrict__ out) {
    int i = blockIdx.x * 256 + threadIdx.x;
    if (i < NPIX) {
        float z = feat[i] + feat[NPIX + i] + feat[2 * NPIX + i] +
                  feat[3 * NPIX + i] + b0[0];
        out[i] = 1.f / (1.f + expf(-z));
    }
}

// ---------------------------------------------------------------------------
// Fallback: one block (128 threads) per pixel, f32 path, no workspace needed.
// ---------------------------------------------------------------------------
__global__ __launch_bounds__(128) void deform_fallback_kernel(
    const float* __restrict__ x, const float* __restrict__ off,
    const float* __restrict__ w0, const float* __restrict__ b0,
    float* __restrict__ out) {
    int p = blockIdx.x;
    int b = p / HWP;
    int hw = p - b * HWP;
    int h = hw / WW;
    int w = hw - h * WW;
    int tid = threadIdx.x;

    const float* offp = off + (size_t)b * 18 * HWP + hw;
    const float* xb = x + (size_t)b * CC * HWP + (size_t)(2 * tid) * HWP;

    float m0 = -INFINITY, m1 = -INFINITY;

#pragma unroll
    for (int k = 0; k < 9; ++k) {
        int kh = k / 3 - 1;
        int kw = k - (k / 3) * 3 - 1;
        float dy = offp[(size_t)(2 * k) * HWP];
        float dx = offp[(size_t)(2 * k + 1) * HWP];
        float py = (float)(h + kh) + dy;
        float px = (float)(w + kw) + dx;
        float y0f = floorf(py), x0f = floorf(px);
        float wy = py - y0f, wx = px - x0f;
        int y0 = (int)y0f, x0 = (int)x0f;
        int y1 = y0 + 1, x1 = x0 + 1;
        bool vy0 = (y0 >= 0) && (y0 < HH);
        bool vy1 = (y1 >= 0) && (y1 < HH);
        bool vx0 = (x0 >= 0) && (x0 < WW);
        bool vx1 = (x1 >= 0) && (x1 < WW);
        int yc0 = min(max(y0, 0), HH - 1);
        int yc1 = min(max(y1, 0), HH - 1);
        int xc0 = min(max(x0, 0), WW - 1);
        int xc1 = min(max(x1, 0), WW - 1);
        float w00 = (1.f - wy) * (1.f - wx) * (float)(vy0 && vx0);
        float w01 = (1.f - wy) * wx * (float)(vy0 && vx1);
        float w10 = wy * (1.f - wx) * (float)(vy1 && vx0);
        float w11 = wy * wx * (float)(vy1 && vx1);

        int o00 = yc0 * WW + xc0, o01 = yc0 * WW + xc1;
        int o10 = yc1 * WW + xc0, o11 = yc1 * WW + xc1;
        float s0 = xb[o00] * w00 + xb[o01] * w01 + xb[o10] * w10 + xb[o11] * w11;
        float s1 = xb[o00 + HWP] * w00 + xb[o01 + HWP] * w01 +
                   xb[o10 + HWP] * w10 + xb[o11 + HWP] * w11;
        m0 = fmaxf(m0, s0);
        m1 = fmaxf(m1, s1);
    }

    float2 wv = reinterpret_cast<const float2*>(w0)[tid];
    float partial = m0 * wv.x + m1 * wv.y;
#pragma unroll
    for (int d = 32; d > 0; d >>= 1) partial += __shfl_down(partial, d, 64);

    __shared__ float red[2];
    if ((tid & 63) == 0) red[tid >> 6] = partial;
    __syncthreads();
    if (tid == 0) {
        float z = red[0] + red[1] + b0[0];
        out[p] = 1.f / (1.f + expf(-z));
    }
}

extern "C" void kernel_launch(void* const* d_in, const int* in_sizes, int n_in,
                              void* d_out, int out_size, void* d_ws, size_t ws_size,
                              hipStream_t stream) {
    const float* x   = (const float*)d_in[0];
    const float* off = (const float*)d_in[1];
    const float* w0  = (const float*)d_in[2];
    const float* b0  = (const float*)d_in[3];
    float* out = (float*)d_out;

    if (ws_size >= XT_BYTES + FEAT_BYTES) {
        char* xT = (char*)d_ws;
        float* feat = (float*)((char*)d_ws + XT_BYTES);
        prep_kernel<<<NT_BLOCKS, 256, 0, stream>>>(x, (ushort*)xT);
        deform_tiled5_kernel<<<NBLK, 512, 0, stream>>>(xT, off, w0, feat);
        combine_kernel<<<(NPIX + 255) / 256, 256, 0, stream>>>(feat, b0, out);
    } else {
        deform_fallback_kernel<<<NPIX, 128, 0, stream>>>(x, off, w0, b0, out);
    }
}